// Round 13
// baseline (336.489 us; speedup 1.0000x reference)
//
#include <hip/hip_runtime.h>
#include <math.h>

#define B 32
#define S 512
#define Q 512
#define I 256
#define O 64
#define SIG_EPS 0.1f
#define LOG_SIG_EPS (-2.3025850929940457f)

// f32 workspace offsets
#define WS_L 0
#define WS_T1 65536
#define WS_LKT 81920
#define WS_M0 98304
#define WS_M1 2195456
#define WS_RHST 4292608
#define WS_D 4816896
#define WS_SPF 5079040
#define WS_U16 5095488
// u16 offsets (units of u16)
#define U_IVH 10485760
#define U_IVL 12582912

#define OUT_MU_ELEMS (B * Q * O)
#define OUT_SIG_ELEMS (B * Q * O * O)
#define OUT_NLL_IDX (OUT_MU_ELEMS + OUT_SIG_ELEMS)

typedef short short8 __attribute__((ext_vector_type(8)));
typedef float f32x4 __attribute__((ext_vector_type(4)));
#define MFMA16(a, b, c) __builtin_amdgcn_mfma_f32_16x16x32_bf16(a, b, c, 0, 0, 0)

struct Params {
  const float *phi_s, *y_s, *phi_q, *y_q, *Km, *La;
  float *Lm, *T1, *LKT, *M0, *M1, *RHST, *Dbuf, *spws;
  unsigned short *IVh, *IVl;
  float *mu, *nll;
  float4 *sig;
};

__device__ __forceinline__ f32x4 mfma3(short8 ah, short8 al, short8 bh, short8 bl, f32x4 c) {
  c = MFMA16(ah, bh, c);
  c = MFMA16(ah, bl, c);
  c = MFMA16(al, bh, c);
  return c;
}

__device__ __forceinline__ unsigned short f2bf(float x) {
  unsigned int u = __float_as_uint(x);
  return (unsigned short)((u + 0x7fffu + ((u >> 16) & 1u)) >> 16);
}
__device__ __forceinline__ float bf2f(unsigned short h) { return __uint_as_float(((unsigned int)h) << 16); }
__device__ __forceinline__ void split2(float x, unsigned short& h, unsigned short& l) {
  h = f2bf(x);
  l = f2bf(x - bf2f(h));
}
__device__ __forceinline__ void split4(float4 v, uint2& H, uint2& L) {
  unsigned short h0, h1, h2, h3, l0, l1, l2, l3;
  split2(v.x, h0, l0); split2(v.y, h1, l1); split2(v.z, h2, l2); split2(v.w, h3, l3);
  H.x = (unsigned)h0 | ((unsigned)h1 << 16); H.y = (unsigned)h2 | ((unsigned)h3 << 16);
  L.x = (unsigned)l0 | ((unsigned)l1 << 16); L.y = (unsigned)l2 | ((unsigned)l3 << 16);
}
__device__ __forceinline__ void cvt8(const float* p, short8& h8, short8& l8) {
  float4 a = *(const float4*)p;
  float4 b = *(const float4*)(p + 4);
  uint2 H0, L0, H1, L1;
  split4(a, H0, L0); split4(b, H1, L1);
  union { uint2 q[2]; short8 s; } uh, ul;
  uh.q[0] = H0; uh.q[1] = H1; ul.q[0] = L0; ul.q[1] = L1;
  h8 = uh.s; l8 = ul.s;
}
__device__ __forceinline__ short8 ld8(const unsigned short* p) { return *(const short8*)(const void*)p; }

__device__ __forceinline__ void fma4x4(const float4 av, const float4 bv, float acc[4][4]) {
  const float ar[4] = {av.x, av.y, av.z, av.w};
  const float br[4] = {bv.x, bv.y, bv.z, bv.w};
#pragma unroll
  for (int i = 0; i < 4; ++i)
#pragma unroll
    for (int j = 0; j < 4; ++j) acc[i][j] += ar[i] * br[j];
}

__device__ __forceinline__ void load_direct64(float* dst, int ds, const float* src, int ss, int t) {
#pragma unroll
  for (int m = 0; m < 4; ++m) {
    int r = (t >> 4) + 16 * m, c4 = (t & 15) * 4;
    *(float4*)&dst[r * ds + c4] = *(const float4*)&src[(size_t)r * ss + c4];
  }
}
__device__ __forceinline__ void load_trans64(float* dst, int ds, const float* src, int ss, int t) {
#pragma unroll
  for (int m = 0; m < 4; ++m) {
    int r = (t >> 4) + 16 * m, c4 = (t & 15) * 4;
    float4 v = *(const float4*)&src[(size_t)r * ss + c4];
    dst[(c4 + 0) * ds + r] = v.x;
    dst[(c4 + 1) * ds + r] = v.y;
    dst[(c4 + 2) * ds + r] = v.z;
    dst[(c4 + 3) * ds + r] = v.w;
  }
}
template <int SA, int SB>
__device__ __forceinline__ void gemm64(const float* At, const float* Bs, int tr, int tc, float acc[4][4]) {
#pragma unroll 8
  for (int kk = 0; kk < 64; ++kk) {
    float4 a = *(const float4*)&At[kk * SA + tr * 4];
    float4 b = *(const float4*)&Bs[kk * SB + tc * 4];
    fma4x4(a, b, acc);
  }
}

#define SC4(V) V.x *= pivinv; V.y *= pivinv; V.z *= pivinv; V.w *= pivinv
#define UP4(V, R) V.x -= g * R.x; V.y -= g * R.y; V.z -= g * R.z; V.w -= g * R.w

template <int TS>
__device__ void gj64(const float* T, float* rowbuf, float* Dout, int t) {
  int r = t >> 2, q = t & 3;
  int lane = t & 63;
  float4 A0 = *(const float4*)&T[r * TS + q * 16 + 0];
  float4 A1 = *(const float4*)&T[r * TS + q * 16 + 4];
  float4 A2 = *(const float4*)&T[r * TS + q * 16 + 8];
  float4 A3 = *(const float4*)&T[r * TS + q * 16 + 12];
#define IC(c) (((q * 16 + (c)) == r) ? 1.f : 0.f)
  float4 I0 = make_float4(IC(0), IC(1), IC(2), IC(3));
  float4 I1 = make_float4(IC(4), IC(5), IC(6), IC(7));
  float4 I2 = make_float4(IC(8), IC(9), IC(10), IC(11));
  float4 I3 = make_float4(IC(12), IC(13), IC(14), IC(15));
#undef IC
  for (int p = 0; p < 64; ++p) {
    float* RA = rowbuf + (p & 1) * 128;
    float* RI = RA + 64;
    if (r == p) {
      ((float4*)&RA[q * 16])[0] = A0; ((float4*)&RA[q * 16])[1] = A1;
      ((float4*)&RA[q * 16])[2] = A2; ((float4*)&RA[q * 16])[3] = A3;
      ((float4*)&RI[q * 16])[0] = I0; ((float4*)&RI[q * 16])[1] = I1;
      ((float4*)&RI[q * 16])[2] = I2; ((float4*)&RI[q * 16])[3] = I3;
    }
    __syncthreads();
    float pivinv = 1.0f / RA[p];
    int sidx = p & 15;
    float4 blk = (sidx < 8) ? ((sidx < 4) ? A0 : A1) : ((sidx < 12) ? A2 : A3);
    int sc = sidx & 3;
    float ap = (sc == 0) ? blk.x : (sc == 1) ? blk.y : (sc == 2) ? blk.z : blk.w;
    float f = __shfl(ap, (lane & ~3) | (p >> 4), 64);
    float4 ra0 = ((const float4*)&RA[q * 16])[0], ra1 = ((const float4*)&RA[q * 16])[1];
    float4 ra2 = ((const float4*)&RA[q * 16])[2], ra3 = ((const float4*)&RA[q * 16])[3];
    float4 ri0 = ((const float4*)&RI[q * 16])[0], ri1 = ((const float4*)&RI[q * 16])[1];
    float4 ri2 = ((const float4*)&RI[q * 16])[2], ri3 = ((const float4*)&RI[q * 16])[3];
    if (r == p) {
      SC4(A0); SC4(A1); SC4(A2); SC4(A3);
      SC4(I0); SC4(I1); SC4(I2); SC4(I3);
    } else {
      float g = f * pivinv;
      UP4(A0, ra0); UP4(A1, ra1); UP4(A2, ra2); UP4(A3, ra3);
      UP4(I0, ri0); UP4(I1, ri1); UP4(I2, ri2); UP4(I3, ri3);
    }
  }
  ((float4*)&Dout[r * 64 + q * 16])[0] = I0;
  ((float4*)&Dout[r * 64 + q * 16])[1] = I1;
  ((float4*)&Dout[r * 64 + q * 16])[2] = I2;
  ((float4*)&Dout[r * 64 + q * 16])[3] = I3;
}

// ================= k_pre: L = La La^T (16 tiles) + T1 = La^T K (4 tiles) + nll zero =================
__global__ __launch_bounds__(256) void k_pre(Params p) {
  __shared__ float smem[2176];
  int blk = blockIdx.x, t = threadIdx.x;
  if (blk == 0 && t == 0) p.nll[0] = 0.f;
  float* sA = smem;
  float* sB = smem + 1088;
  int tr = t >> 4, tc = t & 15;
  float acc[4][4] = {};
  if (blk < 16) {
    int i0 = (blk >> 2) * 64, j0 = (blk & 3) * 64;
    for (int ks = 0; ks < 256; ks += 16) {
      __syncthreads();
#pragma unroll
      for (int m = 0; m < 4; ++m) {
        int r = (t >> 4) + 16 * m, kk = t & 15;
        sA[kk * 68 + r] = p.La[(size_t)(i0 + r) * 256 + ks + kk];
        sB[kk * 68 + r] = p.La[(size_t)(j0 + r) * 256 + ks + kk];
      }
      __syncthreads();
#pragma unroll
      for (int kk = 0; kk < 16; ++kk) {
        float4 a = *(const float4*)&sA[kk * 68 + tr * 4];
        float4 bv = *(const float4*)&sB[kk * 68 + tc * 4];
        fma4x4(a, bv, acc);
      }
    }
#pragma unroll
    for (int mi = 0; mi < 4; ++mi) {
      float4 v = {acc[mi][0], acc[mi][1], acc[mi][2], acc[mi][3]};
      *(float4*)&p.Lm[(size_t)(i0 + tr * 4 + mi) * 256 + j0 + tc * 4] = v;
    }
  } else {
    int i0 = (blk - 16) * 64;
    for (int ks = 0; ks < 256; ks += 16) {
      __syncthreads();
#pragma unroll
      for (int m = 0; m < 4; ++m) {
        int kk = (t >> 6) + 4 * m, c = t & 63;
        sA[kk * 68 + c] = p.La[(size_t)(ks + kk) * 256 + i0 + c];
        sB[kk * 68 + c] = p.Km[(size_t)(ks + kk) * 64 + c];
      }
      __syncthreads();
#pragma unroll
      for (int kk = 0; kk < 16; ++kk) {
        float4 a = *(const float4*)&sA[kk * 68 + tr * 4];
        float4 bv = *(const float4*)&sB[kk * 68 + tc * 4];
        fma4x4(a, bv, acc);
      }
    }
#pragma unroll
    for (int mi = 0; mi < 4; ++mi) {
      float4 v = {acc[mi][0], acc[mi][1], acc[mi][2], acc[mi][3]};
      *(float4*)&p.T1[(size_t)(i0 + tr * 4 + mi) * 64 + tc * 4] = v;
    }
  }
}

// ================= k_gram: inline transpose+split of phi_s/y_s; u<10 sym M (+mirror,+D0),
// u 10-13 RHST, u==14 LK (b<4) =================
__global__ __launch_bounds__(256) void k_gram(Params p) {
  __shared__ float smemf[5632];           // trbuf 64*68 | rowb 256 | Ws 16*64 (u14)
  __shared__ unsigned short smemu[18432]; // 4 planes of 64*72 u16
  float* trbuf = smemf;
  float* rowb = smemf + 4352;
  float* Ws = smemf + 4608;
  unsigned short* PAh = smemu;
  unsigned short* PAl = smemu + 4608;
  unsigned short* PBh = smemu + 9216;
  unsigned short* PBl = smemu + 13824;
  int b = blockIdx.x, u = blockIdx.y, t = threadIdx.x;

  if (u == 14) {  // LK = La @ T1 -> LKT[o][i]  (unchanged from R9)
    if (b >= 4) return;
    int i0 = b * 64;
    int tr = t >> 4, tc = t & 15;
    float acc[4][4] = {};
    for (int ks = 0; ks < 256; ks += 16) {
      __syncthreads();
#pragma unroll
      for (int m = 0; m < 4; ++m) {
        trbuf[(t & 15) * 68 + (t >> 4) + 16 * m] = p.La[(size_t)(i0 + (t >> 4) + 16 * m) * 256 + ks + (t & 15)];
        Ws[((t >> 6) + 4 * m) * 64 + (t & 63)] = p.T1[(size_t)(ks + (t >> 6) + 4 * m) * 64 + (t & 63)];
      }
      __syncthreads();
#pragma unroll
      for (int kk = 0; kk < 16; ++kk) {
        float4 a = *(const float4*)&trbuf[kk * 68 + tr * 4];
        float4 bv = *(const float4*)&Ws[kk * 64 + tc * 4];
        fma4x4(a, bv, acc);
      }
    }
    __syncthreads();
#pragma unroll
    for (int mi = 0; mi < 4; ++mi)
#pragma unroll
      for (int cj = 0; cj < 4; ++cj) trbuf[(tr * 4 + mi) * 68 + tc * 4 + cj] = acc[mi][cj];
    __syncthreads();
    int rr0 = t >> 4, cc4 = (t & 15) * 4;
#pragma unroll
    for (int m = 0; m < 4; ++m) {
      int rr = rr0 + 16 * m;
      float4 v = {trbuf[(cc4 + 0) * 68 + rr], trbuf[(cc4 + 1) * 68 + rr], trbuf[(cc4 + 2) * 68 + rr],
                  trbuf[(cc4 + 3) * 68 + rr]};
      *(float4*)&p.LKT[(size_t)rr * 256 + i0 + cc4] = v;
    }
    return;
  }

  const int TIa[14] = {0, 0, 0, 0, 1, 1, 1, 2, 2, 3, 0, 1, 2, 3};
  const int TJa[14] = {0, 1, 2, 3, 1, 2, 3, 2, 3, 3, 0, 0, 0, 0};
  bool isR = (u >= 10);
  int it = TIa[u], jt = TJa[u];
  int i0 = it * 64, j0 = isR ? 0 : jt * 64;
  int lane = t & 63, w = t >> 6, wr = w >> 1, wc = w & 1;
  int ra = wr * 32 + (lane & 15);   // local A row
  int rb = wc * 32 + (lane & 15);   // local B row
  int klane = (lane >> 4) * 8;
  const float* srcA = p.phi_s + (size_t)b * S * I;
  const float* srcB;
  int strB, colB0;
  if (isR) {
    srcB = p.y_s + (size_t)b * S * O;
    strB = O;
    colB0 = 0;
  } else {
    srcB = srcA;
    strB = I;
    colB0 = j0;
  }
  bool diag = (!isR) && (it == jt);
  unsigned short* QBh = diag ? PAh : PBh;
  unsigned short* QBl = diag ? PAl : PBl;
  int cs = t & 63;          // staged column
  int rs0 = (t >> 6) * 16;  // staged s-row base

  f32x4 acc[2][2] = {};
  for (int cc = 0; cc < 8; ++cc) {
    __syncthreads();
    int sbase = cc * 64;
#pragma unroll
    for (int m = 0; m < 16; ++m) {
      int s = rs0 + m;
      float xa = srcA[(size_t)(sbase + s) * I + i0 + cs];
      unsigned short h, l;
      split2(xa, h, l);
      PAh[cs * 72 + s] = h;
      PAl[cs * 72 + s] = l;
      if (!diag) {
        float xb = srcB[(size_t)(sbase + s) * strB + colB0 + cs];
        split2(xb, h, l);
        PBh[cs * 72 + s] = h;
        PBl[cs * 72 + s] = l;
      }
    }
    __syncthreads();
#pragma unroll
    for (int ks = 0; ks < 64; ks += 32) {
      int kk = ks + klane;
      short8 a0h = ld8(PAh + ra * 72 + kk);
      short8 a1h = ld8(PAh + (ra + 16) * 72 + kk);
      short8 a0l = ld8(PAl + ra * 72 + kk);
      short8 a1l = ld8(PAl + (ra + 16) * 72 + kk);
      short8 b0h = ld8(QBh + rb * 72 + kk);
      short8 b1h = ld8(QBh + (rb + 16) * 72 + kk);
      short8 b0l = ld8(QBl + rb * 72 + kk);
      short8 b1l = ld8(QBl + (rb + 16) * 72 + kk);
      acc[0][0] = mfma3(a0h, a0l, b0h, b0l, acc[0][0]);
      acc[0][1] = mfma3(a0h, a0l, b1h, b1l, acc[0][1]);
      acc[1][0] = mfma3(a1h, a1l, b0h, b0l, acc[1][0]);
      acc[1][1] = mfma3(a1h, a1l, b1h, b1l, acc[1][1]);
    }
  }
  __syncthreads();
#pragma unroll
  for (int ti = 0; ti < 2; ++ti)
#pragma unroll
    for (int tj = 0; tj < 2; ++tj)
#pragma unroll
      for (int r = 0; r < 4; ++r)
        trbuf[(wr * 32 + ti * 16 + (lane >> 4) * 4 + r) * 68 + wc * 32 + tj * 16 + (lane & 15)] = acc[ti][tj][r];
  __syncthreads();
  int rr0 = t >> 4, cc4 = (t & 15) * 4;
  if (!isR) {
    float* Mb = p.M0 + (size_t)b * 65536;
    bool d00 = (it == 0 && jt == 0);
#pragma unroll
    for (int m = 0; m < 4; ++m) {
      int rr = rr0 + 16 * m;
      float4 v = *(float4*)&trbuf[rr * 68 + cc4];
      float4 lv = *(const float4*)&p.Lm[(size_t)(i0 + rr) * 256 + j0 + cc4];
      v.x += lv.x; v.y += lv.y; v.z += lv.z; v.w += lv.w;
      *(float4*)&Mb[(size_t)(i0 + rr) * 256 + j0 + cc4] = v;
      if (d00) *(float4*)&trbuf[rr * 68 + cc4] = v;
    }
    if (it != jt) {
#pragma unroll
      for (int m = 0; m < 4; ++m) {
        int rr = rr0 + 16 * m;
        float4 v = {trbuf[(cc4 + 0) * 68 + rr], trbuf[(cc4 + 1) * 68 + rr], trbuf[(cc4 + 2) * 68 + rr],
                    trbuf[(cc4 + 3) * 68 + rr]};
        float4 lv = *(const float4*)&p.Lm[(size_t)(j0 + rr) * 256 + i0 + cc4];
        v.x += lv.x; v.y += lv.y; v.z += lv.z; v.w += lv.w;
        *(float4*)&Mb[(size_t)(j0 + rr) * 256 + i0 + cc4] = v;
      }
    }
    if (d00) {
      __syncthreads();
      gj64<68>(trbuf, rowb, p.Dbuf + (size_t)b * 4096, t);
    }
  } else {
#pragma unroll
    for (int m = 0; m < 4; ++m) {
      int rr = rr0 + 16 * m;
      float4 v = {trbuf[(cc4 + 0) * 68 + rr], trbuf[(cc4 + 1) * 68 + rr], trbuf[(cc4 + 2) * 68 + rr],
                  trbuf[(cc4 + 3) * 68 + rr]};
      *(float4*)&p.RHST[((size_t)b * 64 + rr) * 256 + i0 + cc4] = v;
    }
  }
}

// ================= k_st: single blocked-GJ step (R9-verbatim); u==16 (kb0 only): RHST += LKT =================
__global__ __launch_bounds__(256) void k_st(Params p, int kb) {
  __shared__ float smem[13056];
  float* shA = smem;
  float* shB = smem + 4352;
  float* shD = smem + 8448;
  float* rowb = smem + 12800;
  int b = blockIdx.x, u = blockIdx.y, t = threadIdx.x;
  if (u == 16) {
    float4* R4 = (float4*)(p.RHST + (size_t)b * 16384);
    const float4* L4 = (const float4*)p.LKT;
#pragma unroll
    for (int m = 0; m < 16; ++m) {
      int idx = m * 256 + t;
      float4 a = R4[idx];
      float4 l = L4[idx];
      a.x += l.x; a.y += l.y; a.z += l.z; a.w += l.w;
      R4[idx] = a;
    }
    return;
  }
  int i = u >> 2, j = u & 3;
  int tr = t >> 4, tc = t & 15;
  const float* Ms = ((kb & 1) ? p.M1 : p.M0) + (size_t)b * 65536;
  float* Md = ((kb & 1) ? p.M0 : p.M1) + (size_t)b * 65536;
  const float* Din = p.Dbuf + (size_t)(kb & 1) * (B * 4096) + (size_t)b * 4096;
  float* Dout = p.Dbuf + (size_t)((kb + 1) & 1) * (B * 4096) + (size_t)b * 4096;
  bool last = (kb == 3);
  unsigned short* Yh = p.IVh + (size_t)b * 65536;
  unsigned short* Yl = p.IVl + (size_t)b * 65536;
  auto STORE = [&](int row, int col, float4 v) {
    if (last) {
      uint2 H, L;
      split4(v, H, L);
      *(uint2*)&Yh[(size_t)row * 256 + col] = H;
      *(uint2*)&Yl[(size_t)row * 256 + col] = L;
    } else {
      *(float4*)&Md[(size_t)row * 256 + col] = v;
    }
  };
  bool ik = (i == kb), jk = (j == kb);
  if (ik && jk) {
#pragma unroll
    for (int m = 0; m < 4; ++m) {
      int r = (t >> 4) + 16 * m, c4 = (t & 15) * 4;
      STORE(kb * 64 + r, kb * 64 + c4, *(const float4*)&Din[r * 64 + c4]);
    }
  } else if (ik) {
    float acc[4][4] = {};
    load_trans64(shA, 68, Din, 64, t);
    load_direct64(shB, 64, &Ms[(size_t)(kb * 64) * 256 + j * 64], 256, t);
    __syncthreads();
    gemm64<68, 64>(shA, shB, tr, tc, acc);
    __syncthreads();
#pragma unroll
    for (int mi = 0; mi < 4; ++mi) {
      float4 v = {acc[mi][0], acc[mi][1], acc[mi][2], acc[mi][3]};
      STORE(kb * 64 + tr * 4 + mi, j * 64 + tc * 4, v);
    }
  } else if (jk) {
    float acc[4][4] = {};
    load_trans64(shA, 68, &Ms[(size_t)(i * 64) * 256 + kb * 64], 256, t);
    load_direct64(shB, 64, Din, 64, t);
    __syncthreads();
    gemm64<68, 64>(shA, shB, tr, tc, acc);
    __syncthreads();
#pragma unroll
    for (int mi = 0; mi < 4; ++mi) {
      float4 v = {-acc[mi][0], -acc[mi][1], -acc[mi][2], -acc[mi][3]};
      STORE(i * 64 + tr * 4 + mi, kb * 64 + tc * 4, v);
    }
  } else {
    float acc[4][4] = {};
    load_trans64(shA, 68, Din, 64, t);
    load_direct64(shB, 64, &Ms[(size_t)(kb * 64) * 256 + j * 64], 256, t);
    load_trans64(shD, 68, &Ms[(size_t)(i * 64) * 256 + kb * 64], 256, t);
    __syncthreads();
    gemm64<68, 64>(shA, shB, tr, tc, acc);
    __syncthreads();
#pragma unroll
    for (int mi = 0; mi < 4; ++mi) {
      float4 v = {acc[mi][0], acc[mi][1], acc[mi][2], acc[mi][3]};
      *(float4*)&shB[(tr * 4 + mi) * 64 + tc * 4] = v;
    }
    __syncthreads();
    float acc2[4][4] = {};
    gemm64<68, 64>(shD, shB, tr, tc, acc2);
    bool la = (kb < 3) && (i == kb + 1) && (j == kb + 1);
    if (la) __syncthreads();
#pragma unroll
    for (int mi = 0; mi < 4; ++mi) {
      size_t off = (size_t)(i * 64 + tr * 4 + mi) * 256 + j * 64 + tc * 4;
      float4 old = *(const float4*)&Ms[off];
      float4 v = {old.x - acc2[mi][0], old.y - acc2[mi][1], old.z - acc2[mi][2], old.w - acc2[mi][3]};
      STORE(i * 64 + tr * 4 + mi, j * 64 + tc * 4, v);
      if (la) *(float4*)&shB[(tr * 4 + mi) * 64 + tc * 4] = v;
    }
    if (la) {
      __syncthreads();
      gj64<64>(shB, rowb, Dout, t);
    }
  }
}

// ================= k_tail: X = phi_q@Minv -> spread -> mu = X@G -> nll (spread exported) =================
__global__ __launch_bounds__(256) void k_tail(Params p) {
  __shared__ float Xlds[32 * 260];
  __shared__ float Gs[64 * 68];
  __shared__ float spf[32];
  __shared__ float ssdl[32];
  int b = blockIdx.x, qb = blockIdx.y * 32, t = threadIdx.x;
  int lane = t & 63, w = t >> 6;
  int klane = (lane >> 4) * 8;
  const float* Pq = p.phi_q + (size_t)b * 512 * 256;

  short8 ah[2][8], al[2][8];
#pragma unroll
  for (int st = 0; st < 2; ++st) {
    int qlane = qb + st * 16 + (lane & 15);
#pragma unroll
    for (int k8 = 0; k8 < 8; ++k8) cvt8(&Pq[(size_t)qlane * 256 + k8 * 32 + klane], ah[st][k8], al[st][k8]);
  }

  const unsigned short* Vh = p.IVh + (size_t)b * 65536;
  const unsigned short* Vl = p.IVl + (size_t)b * 65536;
  for (int jt = w * 4; jt < w * 4 + 4; ++jt) {
    int jrow = jt * 16 + (lane & 15);
    f32x4 acc0 = {}, acc1 = {};
#pragma unroll
    for (int k8 = 0; k8 < 8; ++k8) {
      short8 bh = ld8(Vh + (size_t)jrow * 256 + k8 * 32 + klane);
      short8 bl = ld8(Vl + (size_t)jrow * 256 + k8 * 32 + klane);
      acc0 = mfma3(ah[0][k8], al[0][k8], bh, bl, acc0);
      acc1 = mfma3(ah[1][k8], al[1][k8], bh, bl, acc1);
    }
    int xi = jt * 16 + (lane & 15);
#pragma unroll
    for (int r = 0; r < 4; ++r) {
      Xlds[((lane >> 4) * 4 + r) * 260 + xi] = acc0[r];
      Xlds[(16 + (lane >> 4) * 4 + r) * 260 + xi] = acc1[r];
    }
  }
  __syncthreads();

  {
    int q = t >> 3, c = t & 7;
    const float* Pqr = Pq + (size_t)(qb + q) * 256;
    float sp = 0.f;
#pragma unroll
    for (int i = c * 32; i < c * 32 + 32; i += 4) {
      float4 xv = *(const float4*)&Xlds[q * 260 + i];
      float4 pv = *(const float4*)&Pqr[i];
      sp += xv.x * pv.x + xv.y * pv.y + xv.z * pv.z + xv.w * pv.w;
    }
    sp += __shfl_xor(sp, 1);
    sp += __shfl_xor(sp, 2);
    sp += __shfl_xor(sp, 4);
    if (c == 0) spf[q] = 1.f + sp;
  }

  {
    int q = t >> 3, c = t & 7;
    const float* Gr = p.RHST + (size_t)b * 16384;
    float accv[8] = {};
    for (int ip = 0; ip < 4; ++ip) {
      __syncthreads();
      int grr = t >> 2, gc = (t & 3) * 16;
#pragma unroll
      for (int m = 0; m < 4; ++m)
        *(float4*)&Gs[grr * 68 + gc + m * 4] = *(const float4*)&Gr[(size_t)grr * 256 + ip * 64 + gc + m * 4];
      __syncthreads();
#pragma unroll 2
      for (int i = 0; i < 64; i += 4) {
        float4 xv = *(const float4*)&Xlds[q * 260 + ip * 64 + i];
#pragma unroll
        for (int oo = 0; oo < 8; ++oo) {
          float4 gv = *(const float4*)&Gs[(c + oo * 8) * 68 + i];
          accv[oo] += xv.x * gv.x + xv.y * gv.y + xv.z * gv.z + xv.w * gv.w;
        }
      }
    }
    size_t qg = (size_t)b * 512 + qb + q;
    float ssd8 = 0.f;
#pragma unroll
    for (int oo = 0; oo < 8; ++oo) {
      int o = c + oo * 8;
      p.mu[qg * 64 + o] = accv[oo];
      float d = p.y_q[qg * 64 + o] - accv[oo];
      ssd8 += d * d;
    }
    ssd8 += __shfl_xor(ssd8, 1);
    ssd8 += __shfl_xor(ssd8, 2);
    ssd8 += __shfl_xor(ssd8, 4);
    if (c == 0) ssdl[q] = ssd8;
  }
  __syncthreads();

  if (w == 0) {
    float val = 0.f;
    if (t < 32) {
      float sp = spf[t];
      val = (64.f * (logf(sp) + LOG_SIG_EPS) + ssdl[t] / (sp * SIG_EPS)) * (1.0f / 16384.0f);
    }
#pragma unroll
    for (int off = 32; off; off >>= 1) val += __shfl_down(val, off);
    if (t == 0) atomicAdd(p.nll, val);
  }
  if (t < 32) p.spws[(size_t)b * 512 + qb + t] = spf[t];
}

// ================= k_sig: dedicated streaming sig fill (65536 blocks) =================
__global__ __launch_bounds__(256) void k_sig(const float* __restrict__ spws, float4* __restrict__ sig) {
  size_t idx = (size_t)blockIdx.x * 256 + threadIdx.x;
  int p4 = (int)(idx & 15);
  int o = (int)((idx >> 4) & 63);
  size_t bq = idx >> 10;
  float sv = spws[bq] * SIG_EPS;
  float4 v;
  v.x = (p4 * 4 + 0 == o) ? sv : 0.f;
  v.y = (p4 * 4 + 1 == o) ? sv : 0.f;
  v.z = (p4 * 4 + 2 == o) ? sv : 0.f;
  v.w = (p4 * 4 + 3 == o) ? sv : 0.f;
  sig[idx] = v;
}

extern "C" void kernel_launch(void* const* d_in, const int* in_sizes, int n_in, void* d_out, int out_size,
                              void* d_ws, size_t ws_size, hipStream_t stream) {
  float* ws = (float*)d_ws;
  unsigned short* u16b = (unsigned short*)(ws + WS_U16);
  float* out_mu = (float*)d_out;

  Params p;
  p.phi_s = (const float*)d_in[0];
  p.y_s = (const float*)d_in[1];
  p.phi_q = (const float*)d_in[2];
  p.y_q = (const float*)d_in[3];
  p.Km = (const float*)d_in[4];
  p.La = (const float*)d_in[5];
  p.Lm = ws + WS_L;
  p.T1 = ws + WS_T1;
  p.LKT = ws + WS_LKT;
  p.M0 = ws + WS_M0;
  p.M1 = ws + WS_M1;
  p.RHST = ws + WS_RHST;
  p.Dbuf = ws + WS_D;
  p.spws = ws + WS_SPF;
  p.IVh = u16b + U_IVH;
  p.IVl = u16b + U_IVL;
  p.mu = out_mu;
  p.sig = (float4*)(out_mu + OUT_MU_ELEMS);
  p.nll = out_mu + OUT_NLL_IDX;

  k_pre<<<20, 256, 0, stream>>>(p);
  k_gram<<<dim3(B, 15), 256, 0, stream>>>(p);
  k_st<<<dim3(B, 17), 256, 0, stream>>>(p, 0);
  k_st<<<dim3(B, 16), 256, 0, stream>>>(p, 1);
  k_st<<<dim3(B, 16), 256, 0, stream>>>(p, 2);
  k_st<<<dim3(B, 16), 256, 0, stream>>>(p, 3);
  k_tail<<<dim3(B, 16), 256, 0, stream>>>(p);
  k_sig<<<65536, 256, 0, stream>>>(p.spws, p.sig);
}

// Round 14
// 314.523 us; speedup vs baseline: 1.0698x; 1.0698x over previous
//
#include <hip/hip_runtime.h>
#include <math.h>

#define B 32
#define S 512
#define Q 512
#define I 256
#define O 64
#define SIG_EPS 0.1f
#define LOG_SIG_EPS (-2.3025850929940457f)

// f32 workspace offsets
#define WS_L 0
#define WS_T1 65536
#define WS_LKT 81920
#define WS_M0 98304
#define WS_M1 2195456
#define WS_RHST 4292608
#define WS_D 4816896
#define WS_SPF 5079040
#define WS_U16 5095488
// u16 offsets (units of u16)
#define U_PTH 0
#define U_PTL 4194304
#define U_YTH 8388608
#define U_YTL 9437184
#define U_IVH 10485760
#define U_IVL 12582912

#define OUT_MU_ELEMS (B * Q * O)
#define OUT_SIG_ELEMS (B * Q * O * O)
#define OUT_NLL_IDX (OUT_MU_ELEMS + OUT_SIG_ELEMS)

typedef short short8 __attribute__((ext_vector_type(8)));
typedef float f32x4 __attribute__((ext_vector_type(4)));
#define MFMA16(a, b, c) __builtin_amdgcn_mfma_f32_16x16x32_bf16(a, b, c, 0, 0, 0)

struct Params {
  const float *phi_s, *y_s, *phi_q, *y_q, *Km, *La;
  float *Lm, *T1, *LKT, *M0, *M1, *RHST, *Dbuf, *spws;
  unsigned short *PTh, *PTl, *YTh, *YTl, *IVh, *IVl;
  float *mu, *nll;
  float4 *sig;
};

__device__ __forceinline__ f32x4 mfma3(short8 ah, short8 al, short8 bh, short8 bl, f32x4 c) {
  c = MFMA16(ah, bh, c);
  c = MFMA16(ah, bl, c);
  c = MFMA16(al, bh, c);
  return c;
}

__device__ __forceinline__ unsigned short f2bf(float x) {
  unsigned int u = __float_as_uint(x);
  return (unsigned short)((u + 0x7fffu + ((u >> 16) & 1u)) >> 16);
}
__device__ __forceinline__ float bf2f(unsigned short h) { return __uint_as_float(((unsigned int)h) << 16); }
__device__ __forceinline__ void split2(float x, unsigned short& h, unsigned short& l) {
  h = f2bf(x);
  l = f2bf(x - bf2f(h));
}
__device__ __forceinline__ void split4(float4 v, uint2& H, uint2& L) {
  unsigned short h0, h1, h2, h3, l0, l1, l2, l3;
  split2(v.x, h0, l0); split2(v.y, h1, l1); split2(v.z, h2, l2); split2(v.w, h3, l3);
  H.x = (unsigned)h0 | ((unsigned)h1 << 16); H.y = (unsigned)h2 | ((unsigned)h3 << 16);
  L.x = (unsigned)l0 | ((unsigned)l1 << 16); L.y = (unsigned)l2 | ((unsigned)l3 << 16);
}
__device__ __forceinline__ void cvt8(const float* p, short8& h8, short8& l8) {
  float4 a = *(const float4*)p;
  float4 b = *(const float4*)(p + 4);
  uint2 H0, L0, H1, L1;
  split4(a, H0, L0); split4(b, H1, L1);
  union { uint2 q[2]; short8 s; } uh, ul;
  uh.q[0] = H0; uh.q[1] = H1; ul.q[0] = L0; ul.q[1] = L1;
  h8 = uh.s; l8 = ul.s;
}
__device__ __forceinline__ short8 ld8(const unsigned short* p) { return *(const short8*)(const void*)p; }

__device__ __forceinline__ void fma4x4(const float4 av, const float4 bv, float acc[4][4]) {
  const float ar[4] = {av.x, av.y, av.z, av.w};
  const float br[4] = {bv.x, bv.y, bv.z, bv.w};
#pragma unroll
  for (int i = 0; i < 4; ++i)
#pragma unroll
    for (int j = 0; j < 4; ++j) acc[i][j] += ar[i] * br[j];
}

__device__ __forceinline__ void load_direct64(float* dst, int ds, const float* src, int ss, int t) {
#pragma unroll
  for (int m = 0; m < 4; ++m) {
    int r = (t >> 4) + 16 * m, c4 = (t & 15) * 4;
    *(float4*)&dst[r * ds + c4] = *(const float4*)&src[(size_t)r * ss + c4];
  }
}
__device__ __forceinline__ void load_trans64(float* dst, int ds, const float* src, int ss, int t) {
#pragma unroll
  for (int m = 0; m < 4; ++m) {
    int r = (t >> 4) + 16 * m, c4 = (t & 15) * 4;
    float4 v = *(const float4*)&src[(size_t)r * ss + c4];
    dst[(c4 + 0) * ds + r] = v.x;
    dst[(c4 + 1) * ds + r] = v.y;
    dst[(c4 + 2) * ds + r] = v.z;
    dst[(c4 + 3) * ds + r] = v.w;
  }
}
template <int SA, int SB>
__device__ __forceinline__ void gemm64(const float* At, const float* Bs, int tr, int tc, float acc[4][4]) {
#pragma unroll 8
  for (int kk = 0; kk < 64; ++kk) {
    float4 a = *(const float4*)&At[kk * SA + tr * 4];
    float4 b = *(const float4*)&Bs[kk * SB + tc * 4];
    fma4x4(a, b, acc);
  }
}

#define SC4(V) V.x *= pivinv; V.y *= pivinv; V.z *= pivinv; V.w *= pivinv
#define UP4(V, R) V.x -= g * R.x; V.y -= g * R.y; V.z -= g * R.z; V.w -= g * R.w

template <int TS>
__device__ void gj64(const float* T, float* rowbuf, float* Dout, int t) {
  int r = t >> 2, q = t & 3;
  int lane = t & 63;
  float4 A0 = *(const float4*)&T[r * TS + q * 16 + 0];
  float4 A1 = *(const float4*)&T[r * TS + q * 16 + 4];
  float4 A2 = *(const float4*)&T[r * TS + q * 16 + 8];
  float4 A3 = *(const float4*)&T[r * TS + q * 16 + 12];
#define IC(c) (((q * 16 + (c)) == r) ? 1.f : 0.f)
  float4 I0 = make_float4(IC(0), IC(1), IC(2), IC(3));
  float4 I1 = make_float4(IC(4), IC(5), IC(6), IC(7));
  float4 I2 = make_float4(IC(8), IC(9), IC(10), IC(11));
  float4 I3 = make_float4(IC(12), IC(13), IC(14), IC(15));
#undef IC
  for (int p = 0; p < 64; ++p) {
    float* RA = rowbuf + (p & 1) * 128;
    float* RI = RA + 64;
    if (r == p) {
      ((float4*)&RA[q * 16])[0] = A0; ((float4*)&RA[q * 16])[1] = A1;
      ((float4*)&RA[q * 16])[2] = A2; ((float4*)&RA[q * 16])[3] = A3;
      ((float4*)&RI[q * 16])[0] = I0; ((float4*)&RI[q * 16])[1] = I1;
      ((float4*)&RI[q * 16])[2] = I2; ((float4*)&RI[q * 16])[3] = I3;
    }
    __syncthreads();
    float pivinv = 1.0f / RA[p];
    int sidx = p & 15;
    float4 blk = (sidx < 8) ? ((sidx < 4) ? A0 : A1) : ((sidx < 12) ? A2 : A3);
    int sc = sidx & 3;
    float ap = (sc == 0) ? blk.x : (sc == 1) ? blk.y : (sc == 2) ? blk.z : blk.w;
    float f = __shfl(ap, (lane & ~3) | (p >> 4), 64);
    float4 ra0 = ((const float4*)&RA[q * 16])[0], ra1 = ((const float4*)&RA[q * 16])[1];
    float4 ra2 = ((const float4*)&RA[q * 16])[2], ra3 = ((const float4*)&RA[q * 16])[3];
    float4 ri0 = ((const float4*)&RI[q * 16])[0], ri1 = ((const float4*)&RI[q * 16])[1];
    float4 ri2 = ((const float4*)&RI[q * 16])[2], ri3 = ((const float4*)&RI[q * 16])[3];
    if (r == p) {
      SC4(A0); SC4(A1); SC4(A2); SC4(A3);
      SC4(I0); SC4(I1); SC4(I2); SC4(I3);
    } else {
      float g = f * pivinv;
      UP4(A0, ra0); UP4(A1, ra1); UP4(A2, ra2); UP4(A3, ra3);
      UP4(I0, ri0); UP4(I1, ri1); UP4(I2, ri2); UP4(I3, ri3);
    }
  }
  ((float4*)&Dout[r * 64 + q * 16])[0] = I0;
  ((float4*)&Dout[r * 64 + q * 16])[1] = I1;
  ((float4*)&Dout[r * 64 + q * 16])[2] = I2;
  ((float4*)&Dout[r * 64 + q * 16])[3] = I3;
}

// ================= k_front: cvt (blk<1280) + pre1 L/T1 (blk 1280..1299) + nll zero =================
__global__ __launch_bounds__(256) void k_front(Params p) {
  __shared__ float smem[4352];
  int w = blockIdx.x, t = threadIdx.x;
  if (w == 0 && t == 0) p.nll[0] = 0.f;
  if (w < 1280) {
    unsigned short* Hs = (unsigned short*)smem;
    unsigned short* Lo = Hs + 64 * 68;
    const float* src;
    unsigned short *dh, *dl;
    int sstride;
    if (w < 1024) {
      int b = w >> 5, r = w & 31, ic = r >> 3, sc = r & 7;
      src = p.phi_s + ((size_t)b * 512 + sc * 64) * 256 + ic * 64;
      sstride = 256;
      size_t d0 = ((size_t)b * 256 + ic * 64) * 512 + sc * 64;
      dh = p.PTh + d0; dl = p.PTl + d0;
    } else {
      int qq = w - 1024, b = qq >> 3, sc = qq & 7;
      src = p.y_s + ((size_t)b * 512 + sc * 64) * 64;
      sstride = 64;
      size_t d0 = ((size_t)b * 64) * 512 + sc * 64;
      dh = p.YTh + d0; dl = p.YTl + d0;
    }
    int c = t & 63, rb = (t >> 6) * 16;
#pragma unroll
    for (int m = 0; m < 16; ++m) {
      int s = rb + m;
      float x = src[(size_t)s * sstride + c];
      unsigned short h, l;
      split2(x, h, l);
      Hs[c * 68 + s] = h;
      Lo[c * 68 + s] = l;
    }
    __syncthreads();
    int il0 = t >> 4, c4 = (t & 15) * 4;
#pragma unroll
    for (int m = 0; m < 4; ++m) {
      int il = il0 + 16 * m;
      uint2 H, L;
      H.x = (unsigned)Hs[il * 68 + c4] | ((unsigned)Hs[il * 68 + c4 + 1] << 16);
      H.y = (unsigned)Hs[il * 68 + c4 + 2] | ((unsigned)Hs[il * 68 + c4 + 3] << 16);
      L.x = (unsigned)Lo[il * 68 + c4] | ((unsigned)Lo[il * 68 + c4 + 1] << 16);
      L.y = (unsigned)Lo[il * 68 + c4 + 2] | ((unsigned)Lo[il * 68 + c4 + 3] << 16);
      *(uint2*)&dh[(size_t)il * 512 + c4] = H;
      *(uint2*)&dl[(size_t)il * 512 + c4] = L;
    }
  } else {
    int blk2 = w - 1280;
    float* sA = smem;
    float* sB = smem + 1088;
    int tr = t >> 4, tc = t & 15;
    float acc[4][4] = {};
    if (blk2 < 16) {
      int i0 = (blk2 >> 2) * 64, j0 = (blk2 & 3) * 64;
      for (int ks = 0; ks < 256; ks += 16) {
        __syncthreads();
#pragma unroll
        for (int m = 0; m < 4; ++m) {
          int r = (t >> 4) + 16 * m, kk = t & 15;
          sA[kk * 68 + r] = p.La[(size_t)(i0 + r) * 256 + ks + kk];
          sB[kk * 68 + r] = p.La[(size_t)(j0 + r) * 256 + ks + kk];
        }
        __syncthreads();
#pragma unroll
        for (int kk = 0; kk < 16; ++kk) {
          float4 a = *(const float4*)&sA[kk * 68 + tr * 4];
          float4 bv = *(const float4*)&sB[kk * 68 + tc * 4];
          fma4x4(a, bv, acc);
        }
      }
#pragma unroll
      for (int mi = 0; mi < 4; ++mi) {
        float4 v = {acc[mi][0], acc[mi][1], acc[mi][2], acc[mi][3]};
        *(float4*)&p.Lm[(size_t)(i0 + tr * 4 + mi) * 256 + j0 + tc * 4] = v;
      }
    } else {
      int i0 = (blk2 - 16) * 64;
      for (int ks = 0; ks < 256; ks += 16) {
        __syncthreads();
#pragma unroll
        for (int m = 0; m < 4; ++m) {
          int kk = (t >> 6) + 4 * m, c = t & 63;
          sA[kk * 68 + c] = p.La[(size_t)(ks + kk) * 256 + i0 + c];
          sB[kk * 68 + c] = p.Km[(size_t)(ks + kk) * 64 + c];
        }
        __syncthreads();
#pragma unroll
        for (int kk = 0; kk < 16; ++kk) {
          float4 a = *(const float4*)&sA[kk * 68 + tr * 4];
          float4 bv = *(const float4*)&sB[kk * 68 + tc * 4];
          fma4x4(a, bv, acc);
        }
      }
#pragma unroll
      for (int mi = 0; mi < 4; ++mi) {
        float4 v = {acc[mi][0], acc[mi][1], acc[mi][2], acc[mi][3]};
        *(float4*)&p.T1[(size_t)(i0 + tr * 4 + mi) * 64 + tc * 4] = v;
      }
    }
  }
}

// ================= k_gram: u<10 sym M tiles (+mirror,+D0), u 10-13 RHST, u==14 LK (b<4) =================
__global__ __launch_bounds__(256) void k_gram(Params p) {
  __shared__ float smem[5632];
  float* trbuf = smem;
  float* Ws = smem + 4352;
  float* rowb = smem + 5376;
  int b = blockIdx.x, u = blockIdx.y, t = threadIdx.x;
  if (u == 14) {
    if (b >= 4) return;
    int i0 = b * 64;
    int tr = t >> 4, tc = t & 15;
    float acc[4][4] = {};
    for (int ks = 0; ks < 256; ks += 16) {
      __syncthreads();
#pragma unroll
      for (int m = 0; m < 4; ++m) {
        trbuf[(t & 15) * 68 + (t >> 4) + 16 * m] = p.La[(size_t)(i0 + (t >> 4) + 16 * m) * 256 + ks + (t & 15)];
        Ws[((t >> 6) + 4 * m) * 64 + (t & 63)] = p.T1[(size_t)(ks + (t >> 6) + 4 * m) * 64 + (t & 63)];
      }
      __syncthreads();
#pragma unroll
      for (int kk = 0; kk < 16; ++kk) {
        float4 a = *(const float4*)&trbuf[kk * 68 + tr * 4];
        float4 bv = *(const float4*)&Ws[kk * 64 + tc * 4];
        fma4x4(a, bv, acc);
      }
    }
    __syncthreads();
#pragma unroll
    for (int mi = 0; mi < 4; ++mi)
#pragma unroll
      for (int cj = 0; cj < 4; ++cj) trbuf[(tr * 4 + mi) * 68 + tc * 4 + cj] = acc[mi][cj];
    __syncthreads();
    int rr0 = t >> 4, cc4 = (t & 15) * 4;
#pragma unroll
    for (int m = 0; m < 4; ++m) {
      int rr = rr0 + 16 * m;
      float4 v = {trbuf[(cc4 + 0) * 68 + rr], trbuf[(cc4 + 1) * 68 + rr], trbuf[(cc4 + 2) * 68 + rr],
                  trbuf[(cc4 + 3) * 68 + rr]};
      *(float4*)&p.LKT[(size_t)rr * 256 + i0 + cc4] = v;
    }
    return;
  }
  const int TIa[14] = {0, 0, 0, 0, 1, 1, 1, 2, 2, 3, 0, 1, 2, 3};
  const int TJa[14] = {0, 1, 2, 3, 1, 2, 3, 2, 3, 3, 0, 0, 0, 0};
  bool isR = (u >= 10);
  int it = TIa[u], jt = TJa[u];
  int i0 = it * 64, j0 = isR ? 0 : jt * 64;
  int lane = t & 63, w = t >> 6, wr = w >> 1, wc = w & 1;
  const unsigned short* Ah = p.PTh + (size_t)b * 256 * 512;
  const unsigned short* Al = p.PTl + (size_t)b * 256 * 512;
  const unsigned short* Bh = isR ? (p.YTh + (size_t)b * 64 * 512) : Ah;
  const unsigned short* Bl = isR ? (p.YTl + (size_t)b * 64 * 512) : Al;
  int ra0 = i0 + wr * 32 + (lane & 15);
  int rb0 = j0 + wc * 32 + (lane & 15);
  int klane = (lane >> 4) * 8;
  f32x4 acc[2][2] = {};
  for (int ks = 0; ks < 512; ks += 32) {
    int kk = ks + klane;
    short8 a0h = ld8(Ah + (size_t)ra0 * 512 + kk);
    short8 a1h = ld8(Ah + (size_t)(ra0 + 16) * 512 + kk);
    short8 a0l = ld8(Al + (size_t)ra0 * 512 + kk);
    short8 a1l = ld8(Al + (size_t)(ra0 + 16) * 512 + kk);
    short8 b0h = ld8(Bh + (size_t)rb0 * 512 + kk);
    short8 b1h = ld8(Bh + (size_t)(rb0 + 16) * 512 + kk);
    short8 b0l = ld8(Bl + (size_t)rb0 * 512 + kk);
    short8 b1l = ld8(Bl + (size_t)(rb0 + 16) * 512 + kk);
    acc[0][0] = mfma3(a0h, a0l, b0h, b0l, acc[0][0]);
    acc[0][1] = mfma3(a0h, a0l, b1h, b1l, acc[0][1]);
    acc[1][0] = mfma3(a1h, a1l, b0h, b0l, acc[1][0]);
    acc[1][1] = mfma3(a1h, a1l, b1h, b1l, acc[1][1]);
  }
#pragma unroll
  for (int ti = 0; ti < 2; ++ti)
#pragma unroll
    for (int tj = 0; tj < 2; ++tj)
#pragma unroll
      for (int r = 0; r < 4; ++r)
        trbuf[(wr * 32 + ti * 16 + (lane >> 4) * 4 + r) * 68 + wc * 32 + tj * 16 + (lane & 15)] = acc[ti][tj][r];
  __syncthreads();
  int rr0 = t >> 4, cc4 = (t & 15) * 4;
  if (!isR) {
    float* Mb = p.M0 + (size_t)b * 65536;
    bool d00 = (it == 0 && jt == 0);
#pragma unroll
    for (int m = 0; m < 4; ++m) {
      int rr = rr0 + 16 * m;
      float4 v = *(float4*)&trbuf[rr * 68 + cc4];
      float4 lv = *(const float4*)&p.Lm[(size_t)(i0 + rr) * 256 + j0 + cc4];
      v.x += lv.x; v.y += lv.y; v.z += lv.z; v.w += lv.w;
      *(float4*)&Mb[(size_t)(i0 + rr) * 256 + j0 + cc4] = v;
      if (d00) *(float4*)&trbuf[rr * 68 + cc4] = v;
    }
    if (it != jt) {
#pragma unroll
      for (int m = 0; m < 4; ++m) {
        int rr = rr0 + 16 * m;
        float4 v = {trbuf[(cc4 + 0) * 68 + rr], trbuf[(cc4 + 1) * 68 + rr], trbuf[(cc4 + 2) * 68 + rr],
                    trbuf[(cc4 + 3) * 68 + rr]};
        float4 lv = *(const float4*)&p.Lm[(size_t)(j0 + rr) * 256 + i0 + cc4];
        v.x += lv.x; v.y += lv.y; v.z += lv.z; v.w += lv.w;
        *(float4*)&Mb[(size_t)(j0 + rr) * 256 + i0 + cc4] = v;
      }
    }
    if (d00) {
      __syncthreads();
      gj64<68>(trbuf, rowb, p.Dbuf + (size_t)b * 4096, t);
    }
  } else {
#pragma unroll
    for (int m = 0; m < 4; ++m) {
      int rr = rr0 + 16 * m;
      float4 v = {trbuf[(cc4 + 0) * 68 + rr], trbuf[(cc4 + 1) * 68 + rr], trbuf[(cc4 + 2) * 68 + rr],
                  trbuf[(cc4 + 3) * 68 + rr]};
      *(float4*)&p.RHST[((size_t)b * 64 + rr) * 256 + i0 + cc4] = v;
    }
  }
}

// ================= k_st: blocked-GJ step (u<16); u==16 (kb0 only): RHST += LKT =================
__global__ __launch_bounds__(256) void k_st(Params p, int kb) {
  __shared__ float smem[13056];
  float* shA = smem;
  float* shB = smem + 4352;
  float* shD = smem + 8448;
  float* rowb = smem + 12800;
  int b = blockIdx.x, u = blockIdx.y, t = threadIdx.x;
  if (u == 16) {
    float4* R4 = (float4*)(p.RHST + (size_t)b * 16384);
    const float4* L4 = (const float4*)p.LKT;
#pragma unroll
    for (int m = 0; m < 16; ++m) {
      int idx = m * 256 + t;
      float4 a = R4[idx];
      float4 l = L4[idx];
      a.x += l.x; a.y += l.y; a.z += l.z; a.w += l.w;
      R4[idx] = a;
    }
    return;
  }
  int i = u >> 2, j = u & 3;
  int tr = t >> 4, tc = t & 15;
  const float* Ms = ((kb & 1) ? p.M1 : p.M0) + (size_t)b * 65536;
  float* Md = ((kb & 1) ? p.M0 : p.M1) + (size_t)b * 65536;
  const float* Din = p.Dbuf + (size_t)(kb & 1) * (B * 4096) + (size_t)b * 4096;
  float* Dout = p.Dbuf + (size_t)((kb + 1) & 1) * (B * 4096) + (size_t)b * 4096;
  bool last = (kb == 3);
  unsigned short* Yh = p.IVh + (size_t)b * 65536;
  unsigned short* Yl = p.IVl + (size_t)b * 65536;
  auto STORE = [&](int row, int col, float4 v) {
    if (last) {
      uint2 H, L;
      split4(v, H, L);
      *(uint2*)&Yh[(size_t)row * 256 + col] = H;
      *(uint2*)&Yl[(size_t)row * 256 + col] = L;
    } else {
      *(float4*)&Md[(size_t)row * 256 + col] = v;
    }
  };
  bool ik = (i == kb), jk = (j == kb);
  if (ik && jk) {
#pragma unroll
    for (int m = 0; m < 4; ++m) {
      int r = (t >> 4) + 16 * m, c4 = (t & 15) * 4;
      STORE(kb * 64 + r, kb * 64 + c4, *(const float4*)&Din[r * 64 + c4]);
    }
  } else if (ik) {
    float acc[4][4] = {};
    load_trans64(shA, 68, Din, 64, t);
    load_direct64(shB, 64, &Ms[(size_t)(kb * 64) * 256 + j * 64], 256, t);
    __syncthreads();
    gemm64<68, 64>(shA, shB, tr, tc, acc);
    __syncthreads();
#pragma unroll
    for (int mi = 0; mi < 4; ++mi) {
      float4 v = {acc[mi][0], acc[mi][1], acc[mi][2], acc[mi][3]};
      STORE(kb * 64 + tr * 4 + mi, j * 64 + tc * 4, v);
    }
  } else if (jk) {
    float acc[4][4] = {};
    load_trans64(shA, 68, &Ms[(size_t)(i * 64) * 256 + kb * 64], 256, t);
    load_direct64(shB, 64, Din, 64, t);
    __syncthreads();
    gemm64<68, 64>(shA, shB, tr, tc, acc);
    __syncthreads();
#pragma unroll
    for (int mi = 0; mi < 4; ++mi) {
      float4 v = {-acc[mi][0], -acc[mi][1], -acc[mi][2], -acc[mi][3]};
      STORE(i * 64 + tr * 4 + mi, kb * 64 + tc * 4, v);
    }
  } else {
    float acc[4][4] = {};
    load_trans64(shA, 68, Din, 64, t);
    load_direct64(shB, 64, &Ms[(size_t)(kb * 64) * 256 + j * 64], 256, t);
    load_trans64(shD, 68, &Ms[(size_t)(i * 64) * 256 + kb * 64], 256, t);
    __syncthreads();
    gemm64<68, 64>(shA, shB, tr, tc, acc);
    __syncthreads();
#pragma unroll
    for (int mi = 0; mi < 4; ++mi) {
      float4 v = {acc[mi][0], acc[mi][1], acc[mi][2], acc[mi][3]};
      *(float4*)&shB[(tr * 4 + mi) * 64 + tc * 4] = v;
    }
    __syncthreads();
    float acc2[4][4] = {};
    gemm64<68, 64>(shD, shB, tr, tc, acc2);
    bool la = (kb < 3) && (i == kb + 1) && (j == kb + 1);
    if (la) __syncthreads();
#pragma unroll
    for (int mi = 0; mi < 4; ++mi) {
      size_t off = (size_t)(i * 64 + tr * 4 + mi) * 256 + j * 64 + tc * 4;
      float4 old = *(const float4*)&Ms[off];
      float4 v = {old.x - acc2[mi][0], old.y - acc2[mi][1], old.z - acc2[mi][2], old.w - acc2[mi][3]};
      STORE(i * 64 + tr * 4 + mi, j * 64 + tc * 4, v);
      if (la) *(float4*)&shB[(tr * 4 + mi) * 64 + tc * 4] = v;
    }
    if (la) {
      __syncthreads();
      gj64<64>(shB, rowb, Dout, t);
    }
  }
}

// ================= k_tail: X = phi_q@Minv (jt-dedup) -> spread -> mu = X@G (LDS-staged) -> nll =================
__global__ __launch_bounds__(256) void k_tail(Params p) {
  __shared__ float Xlds[32 * 260];
  __shared__ float Gs[64 * 68];
  __shared__ float spf[32];
  __shared__ float ssdl[32];
  int b = blockIdx.x, qb = blockIdx.y * 32, t = threadIdx.x;
  int lane = t & 63, w = t >> 6;
  int klane = (lane >> 4) * 8;
  const float* Pq = p.phi_q + (size_t)b * 512 * 256;

  short8 ah[2][8], al[2][8];
#pragma unroll
  for (int st = 0; st < 2; ++st) {
    int qlane = qb + st * 16 + (lane & 15);
#pragma unroll
    for (int k8 = 0; k8 < 8; ++k8) cvt8(&Pq[(size_t)qlane * 256 + k8 * 32 + klane], ah[st][k8], al[st][k8]);
  }

  const unsigned short* Vh = p.IVh + (size_t)b * 65536;
  const unsigned short* Vl = p.IVl + (size_t)b * 65536;
  for (int jt = w * 4; jt < w * 4 + 4; ++jt) {
    int jrow = jt * 16 + (lane & 15);
    f32x4 acc0 = {}, acc1 = {};
#pragma unroll
    for (int k8 = 0; k8 < 8; ++k8) {
      short8 bh = ld8(Vh + (size_t)jrow * 256 + k8 * 32 + klane);
      short8 bl = ld8(Vl + (size_t)jrow * 256 + k8 * 32 + klane);
      acc0 = mfma3(ah[0][k8], al[0][k8], bh, bl, acc0);
      acc1 = mfma3(ah[1][k8], al[1][k8], bh, bl, acc1);
    }
    int xi = jt * 16 + (lane & 15);
#pragma unroll
    for (int r = 0; r < 4; ++r) {
      Xlds[((lane >> 4) * 4 + r) * 260 + xi] = acc0[r];
      Xlds[(16 + (lane >> 4) * 4 + r) * 260 + xi] = acc1[r];
    }
  }
  __syncthreads();

  {
    int q = t >> 3, c = t & 7;
    const float* Pqr = Pq + (size_t)(qb + q) * 256;
    float sp = 0.f;
#pragma unroll
    for (int i = c * 32; i < c * 32 + 32; i += 4) {
      float4 xv = *(const float4*)&Xlds[q * 260 + i];
      float4 pv = *(const float4*)&Pqr[i];
      sp += xv.x * pv.x + xv.y * pv.y + xv.z * pv.z + xv.w * pv.w;
    }
    sp += __shfl_xor(sp, 1);
    sp += __shfl_xor(sp, 2);
    sp += __shfl_xor(sp, 4);
    if (c == 0) spf[q] = 1.f + sp;
  }

  {
    int q = t >> 3, c = t & 7;
    const float* Gr = p.RHST + (size_t)b * 16384;
    float accv[8] = {};
    for (int ip = 0; ip < 4; ++ip) {
      __syncthreads();
      int grr = t >> 2, gc = (t & 3) * 16;
#pragma unroll
      for (int m = 0; m < 4; ++m)
        *(float4*)&Gs[grr * 68 + gc + m * 4] = *(const float4*)&Gr[(size_t)grr * 256 + ip * 64 + gc + m * 4];
      __syncthreads();
#pragma unroll 2
      for (int i = 0; i < 64; i += 4) {
        float4 xv = *(const float4*)&Xlds[q * 260 + ip * 64 + i];
#pragma unroll
        for (int oo = 0; oo < 8; ++oo) {
          float4 gv = *(const float4*)&Gs[(c + oo * 8) * 68 + i];
          accv[oo] += xv.x * gv.x + xv.y * gv.y + xv.z * gv.z + xv.w * gv.w;
        }
      }
    }
    size_t qg = (size_t)b * 512 + qb + q;
    float ssd8 = 0.f;
#pragma unroll
    for (int oo = 0; oo < 8; ++oo) {
      int o = c + oo * 8;
      p.mu[qg * 64 + o] = accv[oo];
      float d = p.y_q[qg * 64 + o] - accv[oo];
      ssd8 += d * d;
    }
    ssd8 += __shfl_xor(ssd8, 1);
    ssd8 += __shfl_xor(ssd8, 2);
    ssd8 += __shfl_xor(ssd8, 4);
    if (c == 0) ssdl[q] = ssd8;
  }
  __syncthreads();

  if (w == 0) {
    float val = 0.f;
    if (t < 32) {
      float sp = spf[t];
      val = (64.f * (logf(sp) + LOG_SIG_EPS) + ssdl[t] / (sp * SIG_EPS)) * (1.0f / 16384.0f);
    }
#pragma unroll
    for (int off = 32; off; off >>= 1) val += __shfl_down(val, off);
    if (t == 0) atomicAdd(p.nll, val);
  }
  if (t < 32) p.spws[(size_t)b * 512 + qb + t] = spf[t];
}

// ================= k_sig: streaming sig fill (8192 blocks x 8 float4/thread) =================
__global__ __launch_bounds__(256) void k_sig(const float* __restrict__ spws, float4* __restrict__ sig) {
  size_t base = (size_t)blockIdx.x * 2048 + threadIdx.x;
#pragma unroll
  for (int it = 0; it < 8; ++it) {
    size_t idx = base + (size_t)it * 256;
    int p4 = (int)(idx & 15);
    int o = (int)((idx >> 4) & 63);
    size_t bq = idx >> 10;
    float sv = spws[bq] * SIG_EPS;
    float4 v;
    v.x = (p4 * 4 + 0 == o) ? sv : 0.f;
    v.y = (p4 * 4 + 1 == o) ? sv : 0.f;
    v.z = (p4 * 4 + 2 == o) ? sv : 0.f;
    v.w = (p4 * 4 + 3 == o) ? sv : 0.f;
    sig[idx] = v;
  }
}

extern "C" void kernel_launch(void* const* d_in, const int* in_sizes, int n_in, void* d_out, int out_size,
                              void* d_ws, size_t ws_size, hipStream_t stream) {
  float* ws = (float*)d_ws;
  unsigned short* u16b = (unsigned short*)(ws + WS_U16);
  float* out_mu = (float*)d_out;

  Params p;
  p.phi_s = (const float*)d_in[0];
  p.y_s = (const float*)d_in[1];
  p.phi_q = (const float*)d_in[2];
  p.y_q = (const float*)d_in[3];
  p.Km = (const float*)d_in[4];
  p.La = (const float*)d_in[5];
  p.Lm = ws + WS_L;
  p.T1 = ws + WS_T1;
  p.LKT = ws + WS_LKT;
  p.M0 = ws + WS_M0;
  p.M1 = ws + WS_M1;
  p.RHST = ws + WS_RHST;
  p.Dbuf = ws + WS_D;
  p.spws = ws + WS_SPF;
  p.PTh = u16b + U_PTH;
  p.PTl = u16b + U_PTL;
  p.YTh = u16b + U_YTH;
  p.YTl = u16b + U_YTL;
  p.IVh = u16b + U_IVH;
  p.IVl = u16b + U_IVL;
  p.mu = out_mu;
  p.sig = (float4*)(out_mu + OUT_MU_ELEMS);
  p.nll = out_mu + OUT_NLL_IDX;

  k_front<<<1300, 256, 0, stream>>>(p);
  k_gram<<<dim3(B, 15), 256, 0, stream>>>(p);
  k_st<<<dim3(B, 17), 256, 0, stream>>>(p, 0);
  k_st<<<dim3(B, 16), 256, 0, stream>>>(p, 1);
  k_st<<<dim3(B, 16), 256, 0, stream>>>(p, 2);
  k_st<<<dim3(B, 16), 256, 0, stream>>>(p, 3);
  k_tail<<<dim3(B, 16), 256, 0, stream>>>(p);
  k_sig<<<8192, 256, 0, stream>>>(p.spws, p.sig);
}

// Round 16
// 298.140 us; speedup vs baseline: 1.1286x; 1.0550x over previous
//
#include <hip/hip_runtime.h>
#include <math.h>

#define B 32
#define S 512
#define Q 512
#define I 256
#define O 64
#define SIG_EPS 0.1f
#define LOG_SIG_EPS (-2.3025850929940457f)

// f32 workspace offsets
#define WS_L 0
#define WS_T1 65536
#define WS_LKT 81920
#define WS_M0 98304
#define WS_M1 2195456
#define WS_RHST 4292608
#define WS_D 4816896
#define WS_SPF 5079040
#define WS_U16 5095488
// u16 offsets (units of u16)
#define U_PTH 0
#define U_PTL 4194304
#define U_YTH 8388608
#define U_YTL 9437184
#define U_IVH 10485760
#define U_IVL 12582912

#define OUT_MU_ELEMS (B * Q * O)
#define OUT_SIG_ELEMS (B * Q * O * O)
#define OUT_NLL_IDX (OUT_MU_ELEMS + OUT_SIG_ELEMS)

typedef short short8 __attribute__((ext_vector_type(8)));
typedef float f32x4 __attribute__((ext_vector_type(4)));
#define MFMA16(a, b, c) __builtin_amdgcn_mfma_f32_16x16x32_bf16(a, b, c, 0, 0, 0)

struct Params {
  const float *phi_s, *y_s, *phi_q, *y_q, *Km, *La;
  float *Lm, *T1, *LKT, *M0, *M1, *RHST, *Dbuf, *spws;
  unsigned short *PTh, *PTl, *YTh, *YTl, *IVh, *IVl;
  float *mu, *nll;
  float4 *sig;
};

__device__ __forceinline__ f32x4 mfma3(short8 ah, short8 al, short8 bh, short8 bl, f32x4 c) {
  c = MFMA16(ah, bh, c);
  c = MFMA16(ah, bl, c);
  c = MFMA16(al, bh, c);
  return c;
}

__device__ __forceinline__ unsigned short f2bf(float x) {
  unsigned int u = __float_as_uint(x);
  return (unsigned short)((u + 0x7fffu + ((u >> 16) & 1u)) >> 16);
}
__device__ __forceinline__ float bf2f(unsigned short h) { return __uint_as_float(((unsigned int)h) << 16); }
__device__ __forceinline__ void split2(float x, unsigned short& h, unsigned short& l) {
  h = f2bf(x);
  l = f2bf(x - bf2f(h));
}
__device__ __forceinline__ void split4(float4 v, uint2& H, uint2& L) {
  unsigned short h0, h1, h2, h3, l0, l1, l2, l3;
  split2(v.x, h0, l0); split2(v.y, h1, l1); split2(v.z, h2, l2); split2(v.w, h3, l3);
  H.x = (unsigned)h0 | ((unsigned)h1 << 16); H.y = (unsigned)h2 | ((unsigned)h3 << 16);
  L.x = (unsigned)l0 | ((unsigned)l1 << 16); L.y = (unsigned)l2 | ((unsigned)l3 << 16);
}
__device__ __forceinline__ void cvt8(const float* p, short8& h8, short8& l8) {
  float4 a = *(const float4*)p;
  float4 b = *(const float4*)(p + 4);
  uint2 H0, L0, H1, L1;
  split4(a, H0, L0); split4(b, H1, L1);
  union { uint2 q[2]; short8 s; } uh, ul;
  uh.q[0] = H0; uh.q[1] = H1; ul.q[0] = L0; ul.q[1] = L1;
  h8 = uh.s; l8 = ul.s;
}
__device__ __forceinline__ short8 ld8(const unsigned short* p) { return *(const short8*)(const void*)p; }

__device__ __forceinline__ void fma4x4(const float4 av, const float4 bv, float acc[4][4]) {
  const float ar[4] = {av.x, av.y, av.z, av.w};
  const float br[4] = {bv.x, bv.y, bv.z, bv.w};
#pragma unroll
  for (int i = 0; i < 4; ++i)
#pragma unroll
    for (int j = 0; j < 4; ++j) acc[i][j] += ar[i] * br[j];
}

__device__ __forceinline__ void load_direct64(float* dst, int ds, const float* src, int ss, int t) {
#pragma unroll
  for (int m = 0; m < 4; ++m) {
    int r = (t >> 4) + 16 * m, c4 = (t & 15) * 4;
    *(float4*)&dst[r * ds + c4] = *(const float4*)&src[(size_t)r * ss + c4];
  }
}
__device__ __forceinline__ void load_trans64(float* dst, int ds, const float* src, int ss, int t) {
#pragma unroll
  for (int m = 0; m < 4; ++m) {
    int r = (t >> 4) + 16 * m, c4 = (t & 15) * 4;
    float4 v = *(const float4*)&src[(size_t)r * ss + c4];
    dst[(c4 + 0) * ds + r] = v.x;
    dst[(c4 + 1) * ds + r] = v.y;
    dst[(c4 + 2) * ds + r] = v.z;
    dst[(c4 + 3) * ds + r] = v.w;
  }
}
template <int SA, int SB>
__device__ __forceinline__ void gemm64(const float* At, const float* Bs, int tr, int tc, float acc[4][4]) {
#pragma unroll 8
  for (int kk = 0; kk < 64; ++kk) {
    float4 a = *(const float4*)&At[kk * SA + tr * 4];
    float4 b = *(const float4*)&Bs[kk * SB + tc * 4];
    fma4x4(a, b, acc);
  }
}

#define SC4(V) V.x *= pivinv; V.y *= pivinv; V.z *= pivinv; V.w *= pivinv
#define UP4(V, R) V.x -= g * R.x; V.y -= g * R.y; V.z -= g * R.z; V.w -= g * R.w

template <int TS>
__device__ void gj64(const float* T, float* rowbuf, float* Dout, int t) {
  int r = t >> 2, q = t & 3;
  int lane = t & 63;
  float4 A0 = *(const float4*)&T[r * TS + q * 16 + 0];
  float4 A1 = *(const float4*)&T[r * TS + q * 16 + 4];
  float4 A2 = *(const float4*)&T[r * TS + q * 16 + 8];
  float4 A3 = *(const float4*)&T[r * TS + q * 16 + 12];
#define IC(c) (((q * 16 + (c)) == r) ? 1.f : 0.f)
  float4 I0 = make_float4(IC(0), IC(1), IC(2), IC(3));
  float4 I1 = make_float4(IC(4), IC(5), IC(6), IC(7));
  float4 I2 = make_float4(IC(8), IC(9), IC(10), IC(11));
  float4 I3 = make_float4(IC(12), IC(13), IC(14), IC(15));
#undef IC
  for (int p = 0; p < 64; ++p) {
    float* RA = rowbuf + (p & 1) * 128;
    float* RI = RA + 64;
    if (r == p) {
      ((float4*)&RA[q * 16])[0] = A0; ((float4*)&RA[q * 16])[1] = A1;
      ((float4*)&RA[q * 16])[2] = A2; ((float4*)&RA[q * 16])[3] = A3;
      ((float4*)&RI[q * 16])[0] = I0; ((float4*)&RI[q * 16])[1] = I1;
      ((float4*)&RI[q * 16])[2] = I2; ((float4*)&RI[q * 16])[3] = I3;
    }
    __syncthreads();
    float pivinv = 1.0f / RA[p];
    int sidx = p & 15;
    float4 blk = (sidx < 8) ? ((sidx < 4) ? A0 : A1) : ((sidx < 12) ? A2 : A3);
    int sc = sidx & 3;
    float ap = (sc == 0) ? blk.x : (sc == 1) ? blk.y : (sc == 2) ? blk.z : blk.w;
    float f = __shfl(ap, (lane & ~3) | (p >> 4), 64);
    float4 ra0 = ((const float4*)&RA[q * 16])[0], ra1 = ((const float4*)&RA[q * 16])[1];
    float4 ra2 = ((const float4*)&RA[q * 16])[2], ra3 = ((const float4*)&RA[q * 16])[3];
    float4 ri0 = ((const float4*)&RI[q * 16])[0], ri1 = ((const float4*)&RI[q * 16])[1];
    float4 ri2 = ((const float4*)&RI[q * 16])[2], ri3 = ((const float4*)&RI[q * 16])[3];
    if (r == p) {
      SC4(A0); SC4(A1); SC4(A2); SC4(A3);
      SC4(I0); SC4(I1); SC4(I2); SC4(I3);
    } else {
      float g = f * pivinv;
      UP4(A0, ra0); UP4(A1, ra1); UP4(A2, ra2); UP4(A3, ra3);
      UP4(I0, ri0); UP4(I1, ri1); UP4(I2, ri2); UP4(I3, ri3);
    }
  }
  ((float4*)&Dout[r * 64 + q * 16])[0] = I0;
  ((float4*)&Dout[r * 64 + q * 16])[1] = I1;
  ((float4*)&Dout[r * 64 + q * 16])[2] = I2;
  ((float4*)&Dout[r * 64 + q * 16])[3] = I3;
}

// ================= k_front: cvt (blk<1280) + pre1 L/T1 (blk 1280..1299) + nll zero =================
__global__ __launch_bounds__(256) void k_front(Params p) {
  __shared__ float smem[4352];
  int w = blockIdx.x, t = threadIdx.x;
  if (w == 0 && t == 0) p.nll[0] = 0.f;
  if (w < 1280) {
    unsigned short* Hs = (unsigned short*)smem;
    unsigned short* Lo = Hs + 64 * 68;
    const float* src;
    unsigned short *dh, *dl;
    int sstride;
    if (w < 1024) {
      int b = w >> 5, r = w & 31, ic = r >> 3, sc = r & 7;
      src = p.phi_s + ((size_t)b * 512 + sc * 64) * 256 + ic * 64;
      sstride = 256;
      size_t d0 = ((size_t)b * 256 + ic * 64) * 512 + sc * 64;
      dh = p.PTh + d0; dl = p.PTl + d0;
    } else {
      int qq = w - 1024, b = qq >> 3, sc = qq & 7;
      src = p.y_s + ((size_t)b * 512 + sc * 64) * 64;
      sstride = 64;
      size_t d0 = ((size_t)b * 64) * 512 + sc * 64;
      dh = p.YTh + d0; dl = p.YTl + d0;
    }
    int c = t & 63, rb = (t >> 6) * 16;
#pragma unroll
    for (int m = 0; m < 16; ++m) {
      int s = rb + m;
      float x = src[(size_t)s * sstride + c];
      unsigned short h, l;
      split2(x, h, l);
      Hs[c * 68 + s] = h;
      Lo[c * 68 + s] = l;
    }
    __syncthreads();
    int il0 = t >> 4, c4 = (t & 15) * 4;
#pragma unroll
    for (int m = 0; m < 4; ++m) {
      int il = il0 + 16 * m;
      uint2 H, L;
      H.x = (unsigned)Hs[il * 68 + c4] | ((unsigned)Hs[il * 68 + c4 + 1] << 16);
      H.y = (unsigned)Hs[il * 68 + c4 + 2] | ((unsigned)Hs[il * 68 + c4 + 3] << 16);
      L.x = (unsigned)Lo[il * 68 + c4] | ((unsigned)Lo[il * 68 + c4 + 1] << 16);
      L.y = (unsigned)Lo[il * 68 + c4 + 2] | ((unsigned)Lo[il * 68 + c4 + 3] << 16);
      *(uint2*)&dh[(size_t)il * 512 + c4] = H;
      *(uint2*)&dl[(size_t)il * 512 + c4] = L;
    }
  } else {
    int blk2 = w - 1280;
    float* sA = smem;
    float* sB = smem + 1088;
    int tr = t >> 4, tc = t & 15;
    float acc[4][4] = {};
    if (blk2 < 16) {
      int i0 = (blk2 >> 2) * 64, j0 = (blk2 & 3) * 64;
      for (int ks = 0; ks < 256; ks += 16) {
        __syncthreads();
#pragma unroll
        for (int m = 0; m < 4; ++m) {
          int r = (t >> 4) + 16 * m, kk = t & 15;
          sA[kk * 68 + r] = p.La[(size_t)(i0 + r) * 256 + ks + kk];
          sB[kk * 68 + r] = p.La[(size_t)(j0 + r) * 256 + ks + kk];
        }
        __syncthreads();
#pragma unroll
        for (int kk = 0; kk < 16; ++kk) {
          float4 a = *(const float4*)&sA[kk * 68 + tr * 4];
          float4 bv = *(const float4*)&sB[kk * 68 + tc * 4];
          fma4x4(a, bv, acc);
        }
      }
#pragma unroll
      for (int mi = 0; mi < 4; ++mi) {
        float4 v = {acc[mi][0], acc[mi][1], acc[mi][2], acc[mi][3]};
        *(float4*)&p.Lm[(size_t)(i0 + tr * 4 + mi) * 256 + j0 + tc * 4] = v;
      }
    } else {
      int i0 = (blk2 - 16) * 64;
      for (int ks = 0; ks < 256; ks += 16) {
        __syncthreads();
#pragma unroll
        for (int m = 0; m < 4; ++m) {
          int kk = (t >> 6) + 4 * m, c = t & 63;
          sA[kk * 68 + c] = p.La[(size_t)(ks + kk) * 256 + i0 + c];
          sB[kk * 68 + c] = p.Km[(size_t)(ks + kk) * 64 + c];
        }
        __syncthreads();
#pragma unroll
        for (int kk = 0; kk < 16; ++kk) {
          float4 a = *(const float4*)&sA[kk * 68 + tr * 4];
          float4 bv = *(const float4*)&sB[kk * 68 + tc * 4];
          fma4x4(a, bv, acc);
        }
      }
#pragma unroll
      for (int mi = 0; mi < 4; ++mi) {
        float4 v = {acc[mi][0], acc[mi][1], acc[mi][2], acc[mi][3]};
        *(float4*)&p.T1[(size_t)(i0 + tr * 4 + mi) * 64 + tc * 4] = v;
      }
    }
  }
}

// ================= k_gram: u<10 sym M tiles (+mirror,+D0), u 10-13 RHST, u==14 LK (b<4) =================
__global__ __launch_bounds__(256) void k_gram(Params p) {
  __shared__ float smem[5632];
  float* trbuf = smem;
  float* Ws = smem + 4352;
  float* rowb = smem + 5376;
  int b = blockIdx.x, u = blockIdx.y, t = threadIdx.x;
  if (u == 14) {
    if (b >= 4) return;
    int i0 = b * 64;
    int tr = t >> 4, tc = t & 15;
    float acc[4][4] = {};
    for (int ks = 0; ks < 256; ks += 16) {
      __syncthreads();
#pragma unroll
      for (int m = 0; m < 4; ++m) {
        trbuf[(t & 15) * 68 + (t >> 4) + 16 * m] = p.La[(size_t)(i0 + (t >> 4) + 16 * m) * 256 + ks + (t & 15)];
        Ws[((t >> 6) + 4 * m) * 64 + (t & 63)] = p.T1[(size_t)(ks + (t >> 6) + 4 * m) * 64 + (t & 63)];
      }
      __syncthreads();
#pragma unroll
      for (int kk = 0; kk < 16; ++kk) {
        float4 a = *(const float4*)&trbuf[kk * 68 + tr * 4];
        float4 bv = *(const float4*)&Ws[kk * 64 + tc * 4];
        fma4x4(a, bv, acc);
      }
    }
    __syncthreads();
#pragma unroll
    for (int mi = 0; mi < 4; ++mi)
#pragma unroll
      for (int cj = 0; cj < 4; ++cj) trbuf[(tr * 4 + mi) * 68 + tc * 4 + cj] = acc[mi][cj];
    __syncthreads();
    int rr0 = t >> 4, cc4 = (t & 15) * 4;
#pragma unroll
    for (int m = 0; m < 4; ++m) {
      int rr = rr0 + 16 * m;
      float4 v = {trbuf[(cc4 + 0) * 68 + rr], trbuf[(cc4 + 1) * 68 + rr], trbuf[(cc4 + 2) * 68 + rr],
                  trbuf[(cc4 + 3) * 68 + rr]};
      *(float4*)&p.LKT[(size_t)rr * 256 + i0 + cc4] = v;
    }
    return;
  }
  const int TIa[14] = {0, 0, 0, 0, 1, 1, 1, 2, 2, 3, 0, 1, 2, 3};
  const int TJa[14] = {0, 1, 2, 3, 1, 2, 3, 2, 3, 3, 0, 0, 0, 0};
  bool isR = (u >= 10);
  int it = TIa[u], jt = TJa[u];
  int i0 = it * 64, j0 = isR ? 0 : jt * 64;
  int lane = t & 63, w = t >> 6, wr = w >> 1, wc = w & 1;
  const unsigned short* Ah = p.PTh + (size_t)b * 256 * 512;
  const unsigned short* Al = p.PTl + (size_t)b * 256 * 512;
  const unsigned short* Bh = isR ? (p.YTh + (size_t)b * 64 * 512) : Ah;
  const unsigned short* Bl = isR ? (p.YTl + (size_t)b * 64 * 512) : Al;
  int ra0 = i0 + wr * 32 + (lane & 15);
  int rb0 = j0 + wc * 32 + (lane & 15);
  int klane = (lane >> 4) * 8;
  f32x4 acc[2][2] = {};
  for (int ks = 0; ks < 512; ks += 32) {
    int kk = ks + klane;
    short8 a0h = ld8(Ah + (size_t)ra0 * 512 + kk);
    short8 a1h = ld8(Ah + (size_t)(ra0 + 16) * 512 + kk);
    short8 a0l = ld8(Al + (size_t)ra0 * 512 + kk);
    short8 a1l = ld8(Al + (size_t)(ra0 + 16) * 512 + kk);
    short8 b0h = ld8(Bh + (size_t)rb0 * 512 + kk);
    short8 b1h = ld8(Bh + (size_t)(rb0 + 16) * 512 + kk);
    short8 b0l = ld8(Bl + (size_t)rb0 * 512 + kk);
    short8 b1l = ld8(Bl + (size_t)(rb0 + 16) * 512 + kk);
    acc[0][0] = mfma3(a0h, a0l, b0h, b0l, acc[0][0]);
    acc[0][1] = mfma3(a0h, a0l, b1h, b1l, acc[0][1]);
    acc[1][0] = mfma3(a1h, a1l, b0h, b0l, acc[1][0]);
    acc[1][1] = mfma3(a1h, a1l, b1h, b1l, acc[1][1]);
  }
#pragma unroll
  for (int ti = 0; ti < 2; ++ti)
#pragma unroll
    for (int tj = 0; tj < 2; ++tj)
#pragma unroll
      for (int r = 0; r < 4; ++r)
        trbuf[(wr * 32 + ti * 16 + (lane >> 4) * 4 + r) * 68 + wc * 32 + tj * 16 + (lane & 15)] = acc[ti][tj][r];
  __syncthreads();
  int rr0 = t >> 4, cc4 = (t & 15) * 4;
  if (!isR) {
    float* Mb = p.M0 + (size_t)b * 65536;
    bool d00 = (it == 0 && jt == 0);
#pragma unroll
    for (int m = 0; m < 4; ++m) {
      int rr = rr0 + 16 * m;
      float4 v = *(float4*)&trbuf[rr * 68 + cc4];
      float4 lv = *(const float4*)&p.Lm[(size_t)(i0 + rr) * 256 + j0 + cc4];
      v.x += lv.x; v.y += lv.y; v.z += lv.z; v.w += lv.w;
      *(float4*)&Mb[(size_t)(i0 + rr) * 256 + j0 + cc4] = v;
      if (d00) *(float4*)&trbuf[rr * 68 + cc4] = v;
    }
    if (it != jt) {
#pragma unroll
      for (int m = 0; m < 4; ++m) {
        int rr = rr0 + 16 * m;
        float4 v = {trbuf[(cc4 + 0) * 68 + rr], trbuf[(cc4 + 1) * 68 + rr], trbuf[(cc4 + 2) * 68 + rr],
                    trbuf[(cc4 + 3) * 68 + rr]};
        float4 lv = *(const float4*)&p.Lm[(size_t)(j0 + rr) * 256 + i0 + cc4];
        v.x += lv.x; v.y += lv.y; v.z += lv.z; v.w += lv.w;
        *(float4*)&Mb[(size_t)(j0 + rr) * 256 + i0 + cc4] = v;
      }
    }
    if (d00) {
      __syncthreads();
      gj64<68>(trbuf, rowb, p.Dbuf + (size_t)b * 4096, t);
    }
  } else {
#pragma unroll
    for (int m = 0; m < 4; ++m) {
      int rr = rr0 + 16 * m;
      float4 v = {trbuf[(cc4 + 0) * 68 + rr], trbuf[(cc4 + 1) * 68 + rr], trbuf[(cc4 + 2) * 68 + rr],
                  trbuf[(cc4 + 3) * 68 + rr]};
      *(float4*)&p.RHST[((size_t)b * 64 + rr) * 256 + i0 + cc4] = v;
    }
  }
}

// ================= k_st: blocked-GJ step (u<16); u==16 (kb0 only): RHST += LKT =================
__global__ __launch_bounds__(256) void k_st(Params p, int kb) {
  __shared__ float smem[13056];
  float* shA = smem;
  float* shB = smem + 4352;
  float* shD = smem + 8448;
  float* rowb = smem + 12800;
  int b = blockIdx.x, u = blockIdx.y, t = threadIdx.x;
  if (u == 16) {
    float4* R4 = (float4*)(p.RHST + (size_t)b * 16384);
    const float4* L4 = (const float4*)p.LKT;
#pragma unroll
    for (int m = 0; m < 16; ++m) {
      int idx = m * 256 + t;
      float4 a = R4[idx];
      float4 l = L4[idx];
      a.x += l.x; a.y += l.y; a.z += l.z; a.w += l.w;
      R4[idx] = a;
    }
    return;
  }
  int i = u >> 2, j = u & 3;
  int tr = t >> 4, tc = t & 15;
  const float* Ms = ((kb & 1) ? p.M1 : p.M0) + (size_t)b * 65536;
  float* Md = ((kb & 1) ? p.M0 : p.M1) + (size_t)b * 65536;
  const float* Din = p.Dbuf + (size_t)(kb & 1) * (B * 4096) + (size_t)b * 4096;
  float* Dout = p.Dbuf + (size_t)((kb + 1) & 1) * (B * 4096) + (size_t)b * 4096;
  bool last = (kb == 3);
  unsigned short* Yh = p.IVh + (size_t)b * 65536;
  unsigned short* Yl = p.IVl + (size_t)b * 65536;
  auto STORE = [&](int row, int col, float4 v) {
    if (last) {
      uint2 H, L;
      split4(v, H, L);
      *(uint2*)&Yh[(size_t)row * 256 + col] = H;
      *(uint2*)&Yl[(size_t)row * 256 + col] = L;
    } else {
      *(float4*)&Md[(size_t)row * 256 + col] = v;
    }
  };
  bool ik = (i == kb), jk = (j == kb);
  if (ik && jk) {
#pragma unroll
    for (int m = 0; m < 4; ++m) {
      int r = (t >> 4) + 16 * m, c4 = (t & 15) * 4;
      STORE(kb * 64 + r, kb * 64 + c4, *(const float4*)&Din[r * 64 + c4]);
    }
  } else if (ik) {
    float acc[4][4] = {};
    load_trans64(shA, 68, Din, 64, t);
    load_direct64(shB, 64, &Ms[(size_t)(kb * 64) * 256 + j * 64], 256, t);
    __syncthreads();
    gemm64<68, 64>(shA, shB, tr, tc, acc);
    __syncthreads();
#pragma unroll
    for (int mi = 0; mi < 4; ++mi) {
      float4 v = {acc[mi][0], acc[mi][1], acc[mi][2], acc[mi][3]};
      STORE(kb * 64 + tr * 4 + mi, j * 64 + tc * 4, v);
    }
  } else if (jk) {
    float acc[4][4] = {};
    load_trans64(shA, 68, &Ms[(size_t)(i * 64) * 256 + kb * 64], 256, t);
    load_direct64(shB, 64, Din, 64, t);
    __syncthreads();
    gemm64<68, 64>(shA, shB, tr, tc, acc);
    __syncthreads();
#pragma unroll
    for (int mi = 0; mi < 4; ++mi) {
      float4 v = {-acc[mi][0], -acc[mi][1], -acc[mi][2], -acc[mi][3]};
      STORE(i * 64 + tr * 4 + mi, kb * 64 + tc * 4, v);
    }
  } else {
    float acc[4][4] = {};
    load_trans64(shA, 68, Din, 64, t);
    load_direct64(shB, 64, &Ms[(size_t)(kb * 64) * 256 + j * 64], 256, t);
    load_trans64(shD, 68, &Ms[(size_t)(i * 64) * 256 + kb * 64], 256, t);
    __syncthreads();
    gemm64<68, 64>(shA, shB, tr, tc, acc);
    __syncthreads();
#pragma unroll
    for (int mi = 0; mi < 4; ++mi) {
      float4 v = {acc[mi][0], acc[mi][1], acc[mi][2], acc[mi][3]};
      *(float4*)&shB[(tr * 4 + mi) * 64 + tc * 4] = v;
    }
    __syncthreads();
    float acc2[4][4] = {};
    gemm64<68, 64>(shD, shB, tr, tc, acc2);
    bool la = (kb < 3) && (i == kb + 1) && (j == kb + 1);
    if (la) __syncthreads();
#pragma unroll
    for (int mi = 0; mi < 4; ++mi) {
      size_t off = (size_t)(i * 64 + tr * 4 + mi) * 256 + j * 64 + tc * 4;
      float4 old = *(const float4*)&Ms[off];
      float4 v = {old.x - acc2[mi][0], old.y - acc2[mi][1], old.z - acc2[mi][2], old.w - acc2[mi][3]};
      STORE(i * 64 + tr * 4 + mi, j * 64 + tc * 4, v);
      if (la) *(float4*)&shB[(tr * 4 + mi) * 64 + tc * 4] = v;
    }
    if (la) {
      __syncthreads();
      gj64<64>(shB, rowb, Dout, t);
    }
  }
}

// ================= k_tail: X = phi_q@Minv (jt-dedup) -> spread -> mu = X@G (LDS-staged) -> nll =================
__global__ __launch_bounds__(256) void k_tail(Params p) {
  __shared__ float Xlds[32 * 260];
  __shared__ float Gs[64 * 68];
  __shared__ float spf[32];
  __shared__ float ssdl[32];
  int b = blockIdx.x, qb = blockIdx.y * 32, t = threadIdx.x;
  int lane = t & 63, w = t >> 6;
  int klane = (lane >> 4) * 8;
  const float* Pq = p.phi_q + (size_t)b * 512 * 256;

  short8 ah[2][8], al[2][8];
#pragma unroll
  for (int st = 0; st < 2; ++st) {
    int qlane = qb + st * 16 + (lane & 15);
#pragma unroll
    for (int k8 = 0; k8 < 8; ++k8) cvt8(&Pq[(size_t)qlane * 256 + k8 * 32 + klane], ah[st][k8], al[st][k8]);
  }

  const unsigned short* Vh = p.IVh + (size_t)b * 65536;
  const unsigned short* Vl = p.IVl + (size_t)b * 65536;
  for (int jt = w * 4; jt < w * 4 + 4; ++jt) {
    int jrow = jt * 16 + (lane & 15);
    f32x4 acc0 = {}, acc1 = {};
#pragma unroll
    for (int k8 = 0; k8 < 8; ++k8) {
      short8 bh = ld8(Vh + (size_t)jrow * 256 + k8 * 32 + klane);
      short8 bl = ld8(Vl + (size_t)jrow * 256 + k8 * 32 + klane);
      acc0 = mfma3(ah[0][k8], al[0][k8], bh, bl, acc0);
      acc1 = mfma3(ah[1][k8], al[1][k8], bh, bl, acc1);
    }
    int xi = jt * 16 + (lane & 15);
#pragma unroll
    for (int r = 0; r < 4; ++r) {
      Xlds[((lane >> 4) * 4 + r) * 260 + xi] = acc0[r];
      Xlds[(16 + (lane >> 4) * 4 + r) * 260 + xi] = acc1[r];
    }
  }
  __syncthreads();

  {
    int q = t >> 3, c = t & 7;
    const float* Pqr = Pq + (size_t)(qb + q) * 256;
    float sp = 0.f;
#pragma unroll
    for (int i = c * 32; i < c * 32 + 32; i += 4) {
      float4 xv = *(const float4*)&Xlds[q * 260 + i];
      float4 pv = *(const float4*)&Pqr[i];
      sp += xv.x * pv.x + xv.y * pv.y + xv.z * pv.z + xv.w * pv.w;
    }
    sp += __shfl_xor(sp, 1);
    sp += __shfl_xor(sp, 2);
    sp += __shfl_xor(sp, 4);
    if (c == 0) spf[q] = 1.f + sp;
  }

  {
    int q = t >> 3, c = t & 7;
    const float* Gr = p.RHST + (size_t)b * 16384;
    float accv[8] = {};
    for (int ip = 0; ip < 4; ++ip) {
      __syncthreads();
      int grr = t >> 2, gc = (t & 3) * 16;
#pragma unroll
      for (int m = 0; m < 4; ++m)
        *(float4*)&Gs[grr * 68 + gc + m * 4] = *(const float4*)&Gr[(size_t)grr * 256 + ip * 64 + gc + m * 4];
      __syncthreads();
#pragma unroll 2
      for (int i = 0; i < 64; i += 4) {
        float4 xv = *(const float4*)&Xlds[q * 260 + ip * 64 + i];
#pragma unroll
        for (int oo = 0; oo < 8; ++oo) {
          float4 gv = *(const float4*)&Gs[(c + oo * 8) * 68 + i];
          accv[oo] += xv.x * gv.x + xv.y * gv.y + xv.z * gv.z + xv.w * gv.w;
        }
      }
    }
    size_t qg = (size_t)b * 512 + qb + q;
    float ssd8 = 0.f;
#pragma unroll
    for (int oo = 0; oo < 8; ++oo) {
      int o = c + oo * 8;
      __builtin_nontemporal_store(accv[oo], &p.mu[qg * 64 + o]);
      float d = p.y_q[qg * 64 + o] - accv[oo];
      ssd8 += d * d;
    }
    ssd8 += __shfl_xor(ssd8, 1);
    ssd8 += __shfl_xor(ssd8, 2);
    ssd8 += __shfl_xor(ssd8, 4);
    if (c == 0) ssdl[q] = ssd8;
  }
  __syncthreads();

  if (w == 0) {
    float val = 0.f;
    if (t < 32) {
      float sp = spf[t];
      val = (64.f * (logf(sp) + LOG_SIG_EPS) + ssdl[t] / (sp * SIG_EPS)) * (1.0f / 16384.0f);
    }
#pragma unroll
    for (int off = 32; off; off >>= 1) val += __shfl_down(val, off);
    if (t == 0) atomicAdd(p.nll, val);
  }
  if (t < 32) p.spws[(size_t)b * 512 + qb + t] = spf[t];
}

// ================= k_sig: streaming sig fill (65536 blocks, nontemporal stores) =================
__global__ __launch_bounds__(256) void k_sig(const float* __restrict__ spws, float4* __restrict__ sig) {
  size_t idx = (size_t)blockIdx.x * 256 + threadIdx.x;
  int p4 = (int)(idx & 15);
  int o = (int)((idx >> 4) & 63);
  size_t bq = idx >> 10;
  float sv = spws[bq] * SIG_EPS;
  f32x4 v = {0.f, 0.f, 0.f, 0.f};
  if (p4 * 4 + 0 == o) v[0] = sv;
  if (p4 * 4 + 1 == o) v[1] = sv;
  if (p4 * 4 + 2 == o) v[2] = sv;
  if (p4 * 4 + 3 == o) v[3] = sv;
  __builtin_nontemporal_store(v, (f32x4*)&sig[idx]);
}

extern "C" void kernel_launch(void* const* d_in, const int* in_sizes, int n_in, void* d_out, int out_size,
                              void* d_ws, size_t ws_size, hipStream_t stream) {
  float* ws = (float*)d_ws;
  unsigned short* u16b = (unsigned short*)(ws + WS_U16);
  float* out_mu = (float*)d_out;

  Params p;
  p.phi_s = (const float*)d_in[0];
  p.y_s = (const float*)d_in[1];
  p.phi_q = (const float*)d_in[2];
  p.y_q = (const float*)d_in[3];
  p.Km = (const float*)d_in[4];
  p.La = (const float*)d_in[5];
  p.Lm = ws + WS_L;
  p.T1 = ws + WS_T1;
  p.LKT = ws + WS_LKT;
  p.M0 = ws + WS_M0;
  p.M1 = ws + WS_M1;
  p.RHST = ws + WS_RHST;
  p.Dbuf = ws + WS_D;
  p.spws = ws + WS_SPF;
  p.PTh = u16b + U_PTH;
  p.PTl = u16b + U_PTL;
  p.YTh = u16b + U_YTH;
  p.YTl = u16b + U_YTL;
  p.IVh = u16b + U_IVH;
  p.IVl = u16b + U_IVL;
  p.mu = out_mu;
  p.sig = (float4*)(out_mu + OUT_MU_ELEMS);
  p.nll = out_mu + OUT_NLL_IDX;

  k_front<<<1300, 256, 0, stream>>>(p);
  k_gram<<<dim3(B, 15), 256, 0, stream>>>(p);
  k_st<<<dim3(B, 17), 256, 0, stream>>>(p, 0);
  k_st<<<dim3(B, 16), 256, 0, stream>>>(p, 1);
  k_st<<<dim3(B, 16), 256, 0, stream>>>(p, 2);
  k_st<<<dim3(B, 16), 256, 0, stream>>>(p, 3);
  k_tail<<<dim3(B, 16), 256, 0, stream>>>(p);
  k_sig<<<65536, 256, 0, stream>>>(p.spws, p.sig);
}